// Round 1
// baseline (4306.646 us; speedup 1.0000x reference)
//
#include <hip/hip_runtime.h>
#include <math.h>

#define M_NODES 8192
#define E_DIM   512
#define NTOPK   6
#define ATTN_SCALE 0.04419417382415922f  // 512^-0.5
#define NEG_BIG (-1e38f)

__device__ __forceinline__ float lrelu(float v) { return v > 0.f ? v : 0.01f * v; }

// ---------------------------------------------------------------------------
// Generic tiled fp32 GEMM:  C = act(A[M,K] @ W[N,K]^T + b)
// MODE 0: single W -> C1 (optional leaky-relu)
// MODE 1: two W   -> C1 = A@W1^T+b1, C2 = A@W2^T+b2 (linear)
// MODE 2: A1 = A+A2 (elementwise), A2m = A*A2 ; C1 = lrelu(A1@W1^T+b1)+lrelu(A2m@W2^T+b2)
// BM=BN=64, BK=16, 256 threads, 4x4 micro-tile.
// ---------------------------------------------------------------------------
template <int MODE, bool RELU>
__global__ __launch_bounds__(256) void gemm_kernel(
    const float* __restrict__ A, const float* __restrict__ A2,
    const float* __restrict__ W1, const float* __restrict__ W2,
    const float* __restrict__ b1, const float* __restrict__ b2,
    float* __restrict__ C1, float* __restrict__ C2,
    int Nsz, int Ksz)
{
  constexpr int NA = (MODE == 2) ? 2 : 1;
  constexpr int NB = (MODE == 0) ? 1 : 2;
  constexpr int AI2 = (MODE == 2) ? 1 : 0;
  constexpr int BI2 = (MODE == 0) ? 0 : 1;
  __shared__ float As[NA][64][17];
  __shared__ float Bs[NB][64][17];

  const int tid = threadIdx.x;
  const int m0 = blockIdx.y * 64, n0 = blockIdx.x * 64;
  const int tx4 = (tid & 15) * 4;   // col group
  const int ty4 = (tid >> 4) * 4;   // row group
  const int lr = tid >> 2;          // staging row 0..63
  const int lc = (tid & 3) * 4;     // staging k 0,4,8,12

  float acc[4][4] = {};
  float acc2[4][4] = {};

  for (int k0 = 0; k0 < Ksz; k0 += 16) {
    float4 av = *(const float4*)(A + (size_t)(m0 + lr) * Ksz + k0 + lc);
    if (MODE == 2) {
      float4 qv = *(const float4*)(A2 + (size_t)(m0 + lr) * Ksz + k0 + lc);
      As[0][lr][lc + 0] = av.x + qv.x; As[0][lr][lc + 1] = av.y + qv.y;
      As[0][lr][lc + 2] = av.z + qv.z; As[0][lr][lc + 3] = av.w + qv.w;
      As[AI2][lr][lc + 0] = av.x * qv.x; As[AI2][lr][lc + 1] = av.y * qv.y;
      As[AI2][lr][lc + 2] = av.z * qv.z; As[AI2][lr][lc + 3] = av.w * qv.w;
    } else {
      As[0][lr][lc + 0] = av.x; As[0][lr][lc + 1] = av.y;
      As[0][lr][lc + 2] = av.z; As[0][lr][lc + 3] = av.w;
    }
    float4 wv = *(const float4*)(W1 + (size_t)(n0 + lr) * Ksz + k0 + lc);
    Bs[0][lr][lc + 0] = wv.x; Bs[0][lr][lc + 1] = wv.y;
    Bs[0][lr][lc + 2] = wv.z; Bs[0][lr][lc + 3] = wv.w;
    if (MODE >= 1) {
      float4 w2 = *(const float4*)(W2 + (size_t)(n0 + lr) * Ksz + k0 + lc);
      Bs[BI2][lr][lc + 0] = w2.x; Bs[BI2][lr][lc + 1] = w2.y;
      Bs[BI2][lr][lc + 2] = w2.z; Bs[BI2][lr][lc + 3] = w2.w;
    }
    __syncthreads();
#pragma unroll
    for (int k = 0; k < 16; k++) {
      float a[4], b[4], a2[4], b2[4];
#pragma unroll
      for (int i = 0; i < 4; i++) a[i] = As[0][ty4 + i][k];
#pragma unroll
      for (int j = 0; j < 4; j++) b[j] = Bs[0][tx4 + j][k];
      if (MODE == 2) {
#pragma unroll
        for (int i = 0; i < 4; i++) a2[i] = As[AI2][ty4 + i][k];
      }
      if (MODE >= 1) {
#pragma unroll
        for (int j = 0; j < 4; j++) b2[j] = Bs[BI2][tx4 + j][k];
      }
#pragma unroll
      for (int i = 0; i < 4; i++)
#pragma unroll
        for (int j = 0; j < 4; j++) {
          acc[i][j] = fmaf(a[i], b[j], acc[i][j]);
          if (MODE == 1) acc2[i][j] = fmaf(a[i], b2[j], acc2[i][j]);
          if (MODE == 2) acc2[i][j] = fmaf(a2[i], b2[j], acc2[i][j]);
        }
    }
    __syncthreads();
  }

#pragma unroll
  for (int i = 0; i < 4; i++) {
    const int m = m0 + ty4 + i;
#pragma unroll
    for (int j = 0; j < 4; j++) {
      const int n = n0 + tx4 + j;
      float v1 = acc[i][j] + b1[n];
      if (MODE == 0) {
        C1[(size_t)m * Nsz + n] = RELU ? lrelu(v1) : v1;
      } else if (MODE == 1) {
        C1[(size_t)m * Nsz + n] = v1;
        C2[(size_t)m * Nsz + n] = acc2[i][j] + b2[n];
      } else {
        C1[(size_t)m * Nsz + n] = lrelu(v1) + lrelu(acc2[i][j] + b2[n]);
      }
    }
  }
}

// ---------------------------------------------------------------------------
// Column mean of h over M (axis=1), then h = (h + mean) * 0.5
// ---------------------------------------------------------------------------
__global__ __launch_bounds__(256) void colsum_kernel(const float* __restrict__ h,
                                                     float* __restrict__ colsum)
{
  const int t = threadIdx.x;
  const int r0 = blockIdx.x * 128;
  float s0 = 0.f, s1 = 0.f;
  for (int r = 0; r < 128; r++) {
    s0 += h[(size_t)(r0 + r) * E_DIM + t];
    s1 += h[(size_t)(r0 + r) * E_DIM + 256 + t];
  }
  atomicAdd(&colsum[t], s0);
  atomicAdd(&colsum[t + 256], s1);
}

__global__ __launch_bounds__(256) void hupdate_kernel(float* __restrict__ h,
                                                      const float* __restrict__ colsum)
{
  const size_t i4 = ((size_t)blockIdx.x * 256 + threadIdx.x) * 4;
  float4 v = *(float4*)(h + i4);
  const int c = (int)(i4 & (E_DIM - 1));
  float4 mu = *(const float4*)(colsum + c);
  const float inv_m = 1.f / (float)M_NODES;
  v.x = (v.x + mu.x * inv_m) * 0.5f;
  v.y = (v.y + mu.y * inv_m) * 0.5f;
  v.z = (v.z + mu.z * inv_m) * 0.5f;
  v.w = (v.w + mu.w * inv_m) * 0.5f;
  *(float4*)(h + i4) = v;
}

// ---------------------------------------------------------------------------
// Fused attention-logit GEMM + streaming top-6.
// Block = 32-row strip, sweeps 8192 cols in 128-col tiles; scores never hit HBM.
// ---------------------------------------------------------------------------
__global__ __launch_bounds__(256) void attn_topk_kernel(
    const float* __restrict__ eh, const float* __restrict__ et,
    float* __restrict__ tkv, int* __restrict__ tki)
{
  __shared__ float Ehs[32 * 65];
  __shared__ float Bs[128 * 65];
  __shared__ float Sc[32 * 129];
  const int tid = threadIdx.x;
  const int m0 = blockIdx.x * 32;
  const int tx4 = (tid & 31) * 4;   // cols 0..127
  const int ty4 = (tid >> 5) * 4;   // rows 0..31

  float bv[NTOPK]; int bi[NTOPK];
#pragma unroll
  for (int k = 0; k < NTOPK; k++) { bv[k] = NEG_BIG; bi[k] = 0; }
  float cmin = NEG_BIG; int cslot = 0;

  for (int ct = 0; ct < M_NODES / 128; ct++) {
    const int c0 = ct * 128;
    float acc[4][4] = {};
    for (int kt = 0; kt < E_DIM; kt += 64) {
      __syncthreads();
      for (int idx = tid; idx < 32 * 16; idx += 256) {
        const int r = idx >> 4, cc = (idx & 15) * 4;
        float4 v = *(const float4*)(eh + (size_t)(m0 + r) * E_DIM + kt + cc);
        float* d = &Ehs[r * 65 + cc];
        d[0] = v.x; d[1] = v.y; d[2] = v.z; d[3] = v.w;
      }
      for (int idx = tid; idx < 128 * 16; idx += 256) {
        const int r = idx >> 4, cc = (idx & 15) * 4;
        float4 v = *(const float4*)(et + (size_t)(c0 + r) * E_DIM + kt + cc);
        float* d = &Bs[r * 65 + cc];
        d[0] = v.x; d[1] = v.y; d[2] = v.z; d[3] = v.w;
      }
      __syncthreads();
#pragma unroll 8
      for (int k = 0; k < 64; k++) {
        float a[4], b[4];
#pragma unroll
        for (int i = 0; i < 4; i++) a[i] = Ehs[(ty4 + i) * 65 + k];
#pragma unroll
        for (int j = 0; j < 4; j++) b[j] = Bs[(tx4 + j) * 65 + k];
#pragma unroll
        for (int i = 0; i < 4; i++)
#pragma unroll
          for (int j = 0; j < 4; j++)
            acc[i][j] = fmaf(a[i], b[j], acc[i][j]);
      }
    }
    __syncthreads();
#pragma unroll
    for (int i = 0; i < 4; i++)
#pragma unroll
      for (int j = 0; j < 4; j++)
        Sc[(ty4 + i) * 129 + tx4 + j] = acc[i][j] * ATTN_SCALE;
    __syncthreads();
    if (tid < 32) {
      const int r = tid;
      for (int c = 0; c < 128; c++) {
        const float v = Sc[r * 129 + c];
        if (v > cmin) {
          bv[cslot] = v; bi[cslot] = c0 + c;
          cmin = bv[0]; cslot = 0;
#pragma unroll
          for (int k = 1; k < NTOPK; k++)
            if (bv[k] < cmin) { cmin = bv[k]; cslot = k; }
        }
      }
    }
    __syncthreads();
  }
  if (tid < 32) {
#pragma unroll
    for (int k = 0; k < NTOPK; k++) {
      tkv[(size_t)(m0 + tid) * NTOPK + k] = bv[k];
      tki[(size_t)(m0 + tid) * NTOPK + k] = bi[k];
    }
  }
}

// ---------------------------------------------------------------------------
// Per-row top-k combine: softmax(topk), gather Nb, gate tanh, ka softmax, e_Nh.
// One 64-lane wave per row (block = 4 rows).
// ---------------------------------------------------------------------------
__global__ __launch_bounds__(256) void combine_kernel(
    const float* __restrict__ eh, const float* __restrict__ et,
    const float* __restrict__ tkv, const int* __restrict__ tki,
    float* __restrict__ eNh)
{
  const int lane = threadIdx.x & 63;
  const int m = blockIdx.x * 4 + (threadIdx.x >> 6);

  float w[NTOPK]; int id[NTOPK];
#pragma unroll
  for (int k = 0; k < NTOPK; k++) {
    w[k] = tkv[(size_t)m * NTOPK + k];
    id[k] = tki[(size_t)m * NTOPK + k];
  }
  float mx = w[0];
#pragma unroll
  for (int k = 1; k < NTOPK; k++) mx = fmaxf(mx, w[k]);
  float p[NTOPK]; float s = 0.f;
#pragma unroll
  for (int k = 0; k < NTOPK; k++) { p[k] = expf(w[k] - mx); s += p[k]; }
  const float inv = 1.f / s;
#pragma unroll
  for (int k = 0; k < NTOPK; k++) p[k] *= inv;

  float ehv[8];
#pragma unroll
  for (int i = 0; i < 8; i++) ehv[i] = eh[(size_t)m * E_DIM + lane + 64 * i];

  float ka[NTOPK];
#pragma unroll
  for (int k = 0; k < NTOPK; k++) {
    const float* nr = et + (size_t)id[k] * E_DIM;
    float snb = 0.f, sg = 0.f;
    const float aa = 2.f - p[k], bb = p[k];
#pragma unroll
    for (int i = 0; i < 8; i++) {
      const float nv = nr[lane + 64 * i];
      snb += nv;
      sg += tanhf(fmaf(aa, ehv[i], bb * nv));
    }
#pragma unroll
    for (int off = 32; off; off >>= 1) {
      snb += __shfl_xor(snb, off);
      sg += __shfl_xor(sg, off);
    }
    ka[k] = snb * sg;
  }
  float km = ka[0];
#pragma unroll
  for (int k = 1; k < NTOPK; k++) km = fmaxf(km, ka[k]);
  float kp[NTOPK]; float ks = 0.f;
#pragma unroll
  for (int k = 0; k < NTOPK; k++) { kp[k] = expf(ka[k] - km); ks += kp[k]; }
  const float kinv = 1.f / ks;
#pragma unroll
  for (int i = 0; i < 8; i++) {
    float o = 0.f;
#pragma unroll
    for (int k = 0; k < NTOPK; k++)
      o = fmaf(kp[k], et[(size_t)id[k] * E_DIM + lane + 64 * i], o);
    eNh[(size_t)m * E_DIM + lane + 64 * i] = o * kinv;
  }
}

// ---------------------------------------------------------------------------
// Readout gate: g[m] = a2 . ahid[m] + a2_b (wave per row)
// ---------------------------------------------------------------------------
__global__ __launch_bounds__(256) void gate_g_kernel(
    const float* __restrict__ ahid, const float* __restrict__ a2w,
    const float* __restrict__ a2b, float* __restrict__ g)
{
  const int lane = threadIdx.x & 63;
  const int m = blockIdx.x * 4 + (threadIdx.x >> 6);
  float s = 0.f;
  for (int j = lane; j < 256; j += 64)
    s = fmaf(a2w[j], ahid[(size_t)m * 256 + j], s);
#pragma unroll
  for (int off = 32; off; off >>= 1) s += __shfl_xor(s, off);
  if (lane == 0) g[m] = s + a2b[0];
}

__global__ __launch_bounds__(1024) void softmax_stats_kernel(
    const float* __restrict__ g, float* __restrict__ stats)
{
  __shared__ float red[16];
  __shared__ float red2[16];
  const int t = threadIdx.x;
  float mx = NEG_BIG;
  for (int i = t; i < M_NODES; i += 1024) mx = fmaxf(mx, g[i]);
#pragma unroll
  for (int off = 32; off; off >>= 1) mx = fmaxf(mx, __shfl_xor(mx, off));
  if ((t & 63) == 0) red[t >> 6] = mx;
  __syncthreads();
  float gmx = red[0];
  for (int i = 1; i < 16; i++) gmx = fmaxf(gmx, red[i]);
  float s = 0.f;
  for (int i = t; i < M_NODES; i += 1024) s += expf(g[i] - gmx);
#pragma unroll
  for (int off = 32; off; off >>= 1) s += __shfl_xor(s, off);
  if ((t & 63) == 0) red2[t >> 6] = s;
  __syncthreads();
  if (t == 0) {
    float tot = 0.f;
    for (int i = 0; i < 16; i++) tot += red2[i];
    stats[0] = gmx; stats[1] = tot;
  }
}

__global__ __launch_bounds__(256) void pooled_kernel(
    const float* __restrict__ emb, const float* __restrict__ g,
    const float* __restrict__ stats, float* __restrict__ pooled)
{
  const int t = threadIdx.x;
  const int r0 = blockIdx.x * 128;
  const float mx = stats[0];
  const float inv = 1.f / stats[1];
  float a0 = 0.f, a1 = 0.f;
  for (int r = 0; r < 128; r++) {
    const int m = r0 + r;
    const float wv = expf(g[m] - mx) * inv;
    a0 = fmaf(wv, emb[(size_t)m * E_DIM + t], a0);
    a1 = fmaf(wv, emb[(size_t)m * E_DIM + 256 + t], a1);
  }
  atomicAdd(&pooled[t], a0);
  atomicAdd(&pooled[t + 256], a1);
}

__global__ __launch_bounds__(512) void ln_kernel(
    const float* __restrict__ pooled, const float* __restrict__ lng,
    const float* __restrict__ lnb, float* __restrict__ out)
{
  __shared__ float red[8];
  __shared__ float red2[8];
  const int t = threadIdx.x;
  const float v = pooled[t];
  float s = v;
#pragma unroll
  for (int off = 32; off; off >>= 1) s += __shfl_xor(s, off);
  if ((t & 63) == 0) red[t >> 6] = s;
  __syncthreads();
  float tot = 0.f;
  for (int i = 0; i < 8; i++) tot += red[i];
  const float mu = tot / (float)E_DIM;
  const float d = v - mu;
  float q = d * d;
#pragma unroll
  for (int off = 32; off; off >>= 1) q += __shfl_xor(q, off);
  if ((t & 63) == 0) red2[t >> 6] = q;
  __syncthreads();
  float vt = 0.f;
  for (int i = 0; i < 8; i++) vt += red2[i];
  const float var = vt / (float)E_DIM;
  out[t] = d * rsqrtf(var + 1e-5f) * lng[t] + lnb[t];
}

// ---------------------------------------------------------------------------
extern "C" void kernel_launch(void* const* d_in, const int* in_sizes, int n_in,
                              void* d_out, int out_size, void* d_ws, size_t ws_size,
                              hipStream_t stream)
{
  const float* x     = (const float*)d_in[0];
  const float* fc1_w = (const float*)d_in[1];
  const float* fc1_b = (const float*)d_in[2];
  const float* wh_w  = (const float*)d_in[3];
  const float* wh_b  = (const float*)d_in[4];
  const float* wt_w  = (const float*)d_in[5];
  const float* wt_b  = (const float*)d_in[6];
  const float* l1_w  = (const float*)d_in[7];
  const float* l1_b  = (const float*)d_in[8];
  const float* l2_w  = (const float*)d_in[9];
  const float* l2_b  = (const float*)d_in[10];
  const float* a1_w  = (const float*)d_in[11];
  const float* a1_b  = (const float*)d_in[12];
  const float* a2_w  = (const float*)d_in[13];
  const float* a2_b  = (const float*)d_in[14];
  const float* ln_g  = (const float*)d_in[15];
  const float* ln_b  = (const float*)d_in[16];

  char* ws = (char*)d_ws;
  float* h      = (float*)(ws);                 // 16MB: h -> e_Nh -> ahid
  float* ehb    = (float*)(ws + (16 << 20));    // 16MB: e_h
  float* etb    = (float*)(ws + (32 << 20));    // 16MB: e_t -> emb
  char*  aux    = ws + (48 << 20);
  float* colsum = (float*)aux;
  float* tkv    = (float*)(aux + (64 << 10));
  int*   tki    = (int*)  (aux + (64 << 10) + (256 << 10));
  float* g      = (float*)(aux + (64 << 10) + (512 << 10));
  float* stats  = (float*)(aux + (64 << 10) + (560 << 10));
  float* pooled = (float*)(aux + (64 << 10) + (564 << 10));

  // zero atomic-accumulated buffers (colsum, pooled live in this 1MB span)
  hipMemsetAsync(aux, 0, 1 << 20, stream);

  // 1. h = lrelu(x @ fc1_w^T + b)
  gemm_kernel<0, true><<<dim3(E_DIM / 64, M_NODES / 64), 256, 0, stream>>>(
      x, nullptr, fc1_w, nullptr, fc1_b, nullptr, h, nullptr, E_DIM, 384);
  // 2. h = (h + colmean(h)) * 0.5
  colsum_kernel<<<M_NODES / 128, 256, 0, stream>>>(h, colsum);
  hupdate_kernel<<<(M_NODES * E_DIM) / (256 * 4), 256, 0, stream>>>(h, colsum);
  // 3. e_h, e_t
  gemm_kernel<1, false><<<dim3(E_DIM / 64, M_NODES / 64), 256, 0, stream>>>(
      h, nullptr, wh_w, wt_w, wh_b, wt_b, ehb, etb, E_DIM, E_DIM);
  // 4. fused attn-logit GEMM + streaming top-6
  attn_topk_kernel<<<M_NODES / 32, 256, 0, stream>>>(ehb, etb, tkv, tki);
  // 5. per-row combine -> e_Nh (reuses h buffer)
  combine_kernel<<<M_NODES / 4, 256, 0, stream>>>(ehb, etb, tkv, tki, h);
  // 6. emb = lrelu((e_h+e_Nh)@l1^T+b1) + lrelu((e_h*e_Nh)@l2^T+b2) (into etb)
  gemm_kernel<2, true><<<dim3(E_DIM / 64, M_NODES / 64), 256, 0, stream>>>(
      ehb, h, l1_w, l2_w, l1_b, l2_b, etb, nullptr, E_DIM, E_DIM);
  // 7. ahid = lrelu(emb @ a1^T + b) (into h buffer, 8192x256)
  gemm_kernel<0, true><<<dim3(256 / 64, M_NODES / 64), 256, 0, stream>>>(
      etb, nullptr, a1_w, nullptr, a1_b, nullptr, h, nullptr, 256, E_DIM);
  // 8. g[m] = a2 . ahid[m] + a2_b
  gate_g_kernel<<<M_NODES / 4, 256, 0, stream>>>(h, a2_w, a2_b, g);
  // 9. softmax stats over M
  softmax_stats_kernel<<<1, 1024, 0, stream>>>(g, stats);
  // 10. pooled = sum_m att[m] * emb[m]
  pooled_kernel<<<M_NODES / 128, 256, 0, stream>>>(etb, g, stats, pooled);
  // 11. layernorm -> out
  ln_kernel<<<1, 512, 0, stream>>>(pooled, ln_g, ln_b, (float*)d_out);
}

// Round 2
// 977.132 us; speedup vs baseline: 4.4074x; 4.4074x over previous
//
#include <hip/hip_runtime.h>
#include <math.h>
#include <stdint.h>

#define M_NODES 8192
#define E_DIM   512
#define NTOPK   6
#define ATTN_SCALE 0.04419417382415922f  // 512^-0.5
#define NEG_BIG (-1e38f)

typedef __attribute__((ext_vector_type(8))) short short8;
typedef __attribute__((ext_vector_type(4))) float f32x4;

__device__ __forceinline__ float lrelu(float v) { return v > 0.f ? v : 0.01f * v; }

__device__ __forceinline__ unsigned short f2bf(float f) {
  uint32_t u = __float_as_uint(f);
  uint32_t r = (u + 0x7FFFu + ((u >> 16) & 1u)) >> 16;
  return (unsigned short)r;
}

// async 16B/lane global->LDS (wave-uniform LDS base, lane i lands at base+16i)
__device__ __forceinline__ void async_cp16(const void* gptr, void* lds) {
  auto g1 = reinterpret_cast<const __attribute__((address_space(1))) unsigned int*>(
      reinterpret_cast<uintptr_t>(gptr));
  auto l3 = reinterpret_cast<__attribute__((address_space(3))) unsigned int*>(
      reinterpret_cast<uintptr_t>(lds));
  __builtin_amdgcn_global_load_lds(g1, l3, 16, 0, 0);
}

// ---------------------------------------------------------------------------
// Generic tiled fp32 GEMM:  C = act(A[M,K] @ W[N,K]^T + b)   (unchanged R1)
// ---------------------------------------------------------------------------
template <int MODE, bool RELU>
__global__ __launch_bounds__(256) void gemm_kernel(
    const float* __restrict__ A, const float* __restrict__ A2,
    const float* __restrict__ W1, const float* __restrict__ W2,
    const float* __restrict__ b1, const float* __restrict__ b2,
    float* __restrict__ C1, float* __restrict__ C2,
    int Nsz, int Ksz)
{
  constexpr int NA = (MODE == 2) ? 2 : 1;
  constexpr int NB = (MODE == 0) ? 1 : 2;
  constexpr int AI2 = (MODE == 2) ? 1 : 0;
  constexpr int BI2 = (MODE == 0) ? 0 : 1;
  __shared__ float As[NA][64][17];
  __shared__ float Bs[NB][64][17];

  const int tid = threadIdx.x;
  const int m0 = blockIdx.y * 64, n0 = blockIdx.x * 64;
  const int tx4 = (tid & 15) * 4;
  const int ty4 = (tid >> 4) * 4;
  const int lr = tid >> 2;
  const int lc = (tid & 3) * 4;

  float acc[4][4] = {};
  float acc2[4][4] = {};

  for (int k0 = 0; k0 < Ksz; k0 += 16) {
    float4 av = *(const float4*)(A + (size_t)(m0 + lr) * Ksz + k0 + lc);
    if (MODE == 2) {
      float4 qv = *(const float4*)(A2 + (size_t)(m0 + lr) * Ksz + k0 + lc);
      As[0][lr][lc + 0] = av.x + qv.x; As[0][lr][lc + 1] = av.y + qv.y;
      As[0][lr][lc + 2] = av.z + qv.z; As[0][lr][lc + 3] = av.w + qv.w;
      As[AI2][lr][lc + 0] = av.x * qv.x; As[AI2][lr][lc + 1] = av.y * qv.y;
      As[AI2][lr][lc + 2] = av.z * qv.z; As[AI2][lr][lc + 3] = av.w * qv.w;
    } else {
      As[0][lr][lc + 0] = av.x; As[0][lr][lc + 1] = av.y;
      As[0][lr][lc + 2] = av.z; As[0][lr][lc + 3] = av.w;
    }
    float4 wv = *(const float4*)(W1 + (size_t)(n0 + lr) * Ksz + k0 + lc);
    Bs[0][lr][lc + 0] = wv.x; Bs[0][lr][lc + 1] = wv.y;
    Bs[0][lr][lc + 2] = wv.z; Bs[0][lr][lc + 3] = wv.w;
    if (MODE >= 1) {
      float4 w2 = *(const float4*)(W2 + (size_t)(n0 + lr) * Ksz + k0 + lc);
      Bs[BI2][lr][lc + 0] = w2.x; Bs[BI2][lr][lc + 1] = w2.y;
      Bs[BI2][lr][lc + 2] = w2.z; Bs[BI2][lr][lc + 3] = w2.w;
    }
    __syncthreads();
#pragma unroll
    for (int k = 0; k < 16; k++) {
      float a[4], b[4], a2[4], b2[4];
#pragma unroll
      for (int i = 0; i < 4; i++) a[i] = As[0][ty4 + i][k];
#pragma unroll
      for (int j = 0; j < 4; j++) b[j] = Bs[0][tx4 + j][k];
      if (MODE == 2) {
#pragma unroll
        for (int i = 0; i < 4; i++) a2[i] = As[AI2][ty4 + i][k];
      }
      if (MODE >= 1) {
#pragma unroll
        for (int j = 0; j < 4; j++) b2[j] = Bs[BI2][tx4 + j][k];
      }
#pragma unroll
      for (int i = 0; i < 4; i++)
#pragma unroll
        for (int j = 0; j < 4; j++) {
          acc[i][j] = fmaf(a[i], b[j], acc[i][j]);
          if (MODE == 1) acc2[i][j] = fmaf(a[i], b2[j], acc2[i][j]);
          if (MODE == 2) acc2[i][j] = fmaf(a2[i], b2[j], acc2[i][j]);
        }
    }
    __syncthreads();
  }

#pragma unroll
  for (int i = 0; i < 4; i++) {
    const int m = m0 + ty4 + i;
#pragma unroll
    for (int j = 0; j < 4; j++) {
      const int n = n0 + tx4 + j;
      float v1 = acc[i][j] + b1[n];
      if (MODE == 0) {
        C1[(size_t)m * Nsz + n] = RELU ? lrelu(v1) : v1;
      } else if (MODE == 1) {
        C1[(size_t)m * Nsz + n] = v1;
        C2[(size_t)m * Nsz + n] = acc2[i][j] + b2[n];
      } else {
        C1[(size_t)m * Nsz + n] = lrelu(v1) + lrelu(acc2[i][j] + b2[n]);
      }
    }
  }
}

// ---------------------------------------------------------------------------
// Column mean of h over M, then h = (h + mean) * 0.5
// ---------------------------------------------------------------------------
__global__ __launch_bounds__(256) void colsum_kernel(const float* __restrict__ h,
                                                     float* __restrict__ colsum)
{
  const int t = threadIdx.x;
  const int r0 = blockIdx.x * 128;
  float s0 = 0.f, s1 = 0.f;
  for (int r = 0; r < 128; r++) {
    s0 += h[(size_t)(r0 + r) * E_DIM + t];
    s1 += h[(size_t)(r0 + r) * E_DIM + 256 + t];
  }
  atomicAdd(&colsum[t], s0);
  atomicAdd(&colsum[t + 256], s1);
}

__global__ __launch_bounds__(256) void hupdate_kernel(float* __restrict__ h,
                                                      const float* __restrict__ colsum)
{
  const size_t i4 = ((size_t)blockIdx.x * 256 + threadIdx.x) * 4;
  float4 v = *(float4*)(h + i4);
  const int c = (int)(i4 & (E_DIM - 1));
  float4 mu = *(const float4*)(colsum + c);
  const float inv_m = 1.f / (float)M_NODES;
  v.x = (v.x + mu.x * inv_m) * 0.5f;
  v.y = (v.y + mu.y * inv_m) * 0.5f;
  v.z = (v.z + mu.z * inv_m) * 0.5f;
  v.w = (v.w + mu.w * inv_m) * 0.5f;
  *(float4*)(h + i4) = v;
}

// ---------------------------------------------------------------------------
// Cast e_h (×scale) and e_t to bf16 in MFMA-fragment-tiled layout:
// element (m,k) -> block b=(m>>4)*16+(k>>5); within = ((m&15)+16*((k>>3)&3))*8+(k&7)
// ---------------------------------------------------------------------------
__global__ __launch_bounds__(256) void cast_tiled_kernel(
    const float* __restrict__ eh, const float* __restrict__ et,
    unsigned short* __restrict__ ehT, unsigned short* __restrict__ etT)
{
  const int gid = blockIdx.x * 256 + threadIdx.x;  // 0 .. 8192*64-1
  const int which = blockIdx.y;
  const float* src = which ? et : eh;
  unsigned short* dst = which ? etT : ehT;
  const float sc = which ? 1.f : ATTN_SCALE;
  const int m = gid >> 6, k8 = gid & 63;
  const float* p = src + (size_t)m * E_DIM + k8 * 8;
  float4 v0 = ((const float4*)p)[0];
  float4 v1 = ((const float4*)p)[1];
  const int b = (m >> 4) * 16 + (k8 >> 2);
  const int within = ((m & 15) + 16 * (k8 & 3)) * 8;
  unsigned short* q = dst + (size_t)b * 512 + within;
  unsigned short hh[8];
  hh[0] = f2bf(v0.x * sc); hh[1] = f2bf(v0.y * sc);
  hh[2] = f2bf(v0.z * sc); hh[3] = f2bf(v0.w * sc);
  hh[4] = f2bf(v1.x * sc); hh[5] = f2bf(v1.y * sc);
  hh[6] = f2bf(v1.z * sc); hh[7] = f2bf(v1.w * sc);
  uint4 pk;
  pk.x = (uint32_t)hh[0] | ((uint32_t)hh[1] << 16);
  pk.y = (uint32_t)hh[2] | ((uint32_t)hh[3] << 16);
  pk.z = (uint32_t)hh[4] | ((uint32_t)hh[5] << 16);
  pk.w = (uint32_t)hh[6] | ((uint32_t)hh[7] << 16);
  *(uint4*)q = pk;
}

// ---------------------------------------------------------------------------
// Streaming top-6 state
// ---------------------------------------------------------------------------
struct Top6 { float v[NTOPK]; int id[NTOPK]; float cmin; int cslot; };
__device__ __forceinline__ void t6_init(Top6& t) {
#pragma unroll
  for (int k = 0; k < NTOPK; k++) { t.v[k] = NEG_BIG; t.id[k] = 0; }
  t.cmin = NEG_BIG; t.cslot = 0;
}
__device__ __forceinline__ void t6_ins(Top6& t, float vv, int ii) {
  if (vv > t.cmin) {
    t.v[t.cslot] = vv; t.id[t.cslot] = ii;
    t.cmin = t.v[0]; t.cslot = 0;
#pragma unroll
    for (int k = 1; k < NTOPK; k++)
      if (t.v[k] < t.cmin) { t.cmin = t.v[k]; t.cslot = k; }
  }
}

// ---------------------------------------------------------------------------
// bf16 MFMA attention-logit GEMM + streaming top-6.
// grid (4 col-chunks, 64 row-strips); block 256 (4 waves).
// Per col-tile: 128x128x512 MFMA GEMM (2-barrier K-loop, global_load_lds
// staging into frag-tiled LDS), scores -> LDS, per-row top-6 scan.
// ---------------------------------------------------------------------------
__global__ __launch_bounds__(256) void attn_mfma_topk(
    const unsigned short* __restrict__ ehT, const unsigned short* __restrict__ etT,
    float* __restrict__ tkv4, int* __restrict__ tki4)
{
  __shared__ unsigned short As[8 * 512];   // 8KB: 8 frag-blocks (16 rows x 32 k)
  __shared__ unsigned short Bs[8 * 512];   // 8KB
  __shared__ float Sc[128 * 132];          // 66KB score tile (+pad)

  const int tid = threadIdx.x;
  const int lane = tid & 63;
  const int w = tid >> 6;
  const int wr = w >> 1, wc = w & 1;
  const int m0 = blockIdx.y * 128;
  const int cchunk = blockIdx.x;
  const int cbase = cchunk * 2048;

  const int r = tid & 127;   // scan row
  const int hc = tid >> 7;   // scan col half (wave-uniform)

  Top6 t; t6_init(t);

  const int lrow = (lane >> 4) * 4;   // C-frag row base
  const int lcol = lane & 15;         // C-frag col

  for (int ct = 0; ct < 16; ct++) {
    const int n0 = cbase + ct * 128;
    f32x4 acc[4][4];
#pragma unroll
    for (int i = 0; i < 4; i++)
#pragma unroll
      for (int j = 0; j < 4; j++) acc[i][j] = (f32x4){0.f, 0.f, 0.f, 0.f};

    for (int kt = 0; kt < 16; kt++) {
      // stage A(128x32) + B(128x32) frag-blocks; wave w does segs {w, w+4}
      {
        const int s0 = w, s1 = w + 4;
        const unsigned short* ga0 = ehT + ((size_t)((m0 >> 4) + s0) * 16 + kt) * 512 + lane * 8;
        const unsigned short* ga1 = ehT + ((size_t)((m0 >> 4) + s1) * 16 + kt) * 512 + lane * 8;
        const unsigned short* gb0 = etT + ((size_t)((n0 >> 4) + s0) * 16 + kt) * 512 + lane * 8;
        const unsigned short* gb1 = etT + ((size_t)((n0 >> 4) + s1) * 16 + kt) * 512 + lane * 8;
        async_cp16(ga0, &As[s0 * 512]);
        async_cp16(ga1, &As[s1 * 512]);
        async_cp16(gb0, &Bs[s0 * 512]);
        async_cp16(gb1, &Bs[s1 * 512]);
      }
      __syncthreads();
      short8 a[4], b[4];
#pragma unroll
      for (int i = 0; i < 4; i++) a[i] = *(const short8*)&As[(wr * 4 + i) * 512 + lane * 8];
#pragma unroll
      for (int j = 0; j < 4; j++) b[j] = *(const short8*)&Bs[(wc * 4 + j) * 512 + lane * 8];
#pragma unroll
      for (int i = 0; i < 4; i++)
#pragma unroll
        for (int j = 0; j < 4; j++)
          acc[i][j] = __builtin_amdgcn_mfma_f32_16x16x32_bf16(a[i], b[j], acc[i][j], 0, 0, 0);
      __syncthreads();
    }

    // write scores to LDS (C layout: col=lane&15, row=quad*4+reg)
#pragma unroll
    for (int i = 0; i < 4; i++) {
      const int row = wr * 64 + i * 16 + lrow;
#pragma unroll
      for (int j = 0; j < 4; j++) {
        const int col = wc * 64 + j * 16 + lcol;
        Sc[(row + 0) * 132 + col] = acc[i][j][0];
        Sc[(row + 1) * 132 + col] = acc[i][j][1];
        Sc[(row + 2) * 132 + col] = acc[i][j][2];
        Sc[(row + 3) * 132 + col] = acc[i][j][3];
      }
    }
    __syncthreads();

    // per-row scan of 64 cols (float4)
    const float* srow = &Sc[r * 132 + hc * 64];
    const int cg0 = n0 + hc * 64;
#pragma unroll 4
    for (int c4 = 0; c4 < 16; c4++) {
      float4 v = *(const float4*)(srow + c4 * 4);
      const int cg = cg0 + c4 * 4;
      t6_ins(t, v.x, cg + 0);
      t6_ins(t, v.y, cg + 1);
      t6_ins(t, v.z, cg + 2);
      t6_ins(t, v.w, cg + 3);
    }
    // no trailing barrier needed: next tile's K-loop barriers order Sc reuse
  }

  // merge the two col-half lists per row through LDS
  __syncthreads();
  if (hc == 1) {
#pragma unroll
    for (int k = 0; k < NTOPK; k++) {
      Sc[r * 132 + k] = t.v[k];
      Sc[r * 132 + 8 + k] = __int_as_float(t.id[k]);
    }
  }
  __syncthreads();
  if (hc == 0) {
#pragma unroll
    for (int k = 0; k < NTOPK; k++)
      t6_ins(t, Sc[r * 132 + k], __float_as_int(Sc[r * 132 + 8 + k]));
    const size_t base = ((size_t)(m0 + r) * 4 + cchunk) * NTOPK;
#pragma unroll
    for (int k = 0; k < NTOPK; k++) {
      tkv4[base + k] = t.v[k];
      tki4[base + k] = t.id[k];
    }
  }
}

// ---------------------------------------------------------------------------
// Per-row combine: merge 4 chunk top-6 lists -> global top-6, softmax, gather,
// gate tanh, ka softmax, e_Nh. One wave per row.
// ---------------------------------------------------------------------------
__global__ __launch_bounds__(256) void combine_kernel(
    const float* __restrict__ eh, const float* __restrict__ et,
    const float* __restrict__ tkv4, const int* __restrict__ tki4,
    float* __restrict__ eNh)
{
  const int lane = threadIdx.x & 63;
  const int m = blockIdx.x * 4 + (threadIdx.x >> 6);

  Top6 t; t6_init(t);
  for (int l = 0; l < 4 * NTOPK; l++)
    t6_ins(t, tkv4[(size_t)m * 24 + l], tki4[(size_t)m * 24 + l]);

  float w[NTOPK]; int id[NTOPK];
#pragma unroll
  for (int k = 0; k < NTOPK; k++) { w[k] = t.v[k]; id[k] = t.id[k]; }

  float mx = w[0];
#pragma unroll
  for (int k = 1; k < NTOPK; k++) mx = fmaxf(mx, w[k]);
  float p[NTOPK]; float s = 0.f;
#pragma unroll
  for (int k = 0; k < NTOPK; k++) { p[k] = expf(w[k] - mx); s += p[k]; }
  const float inv = 1.f / s;
#pragma unroll
  for (int k = 0; k < NTOPK; k++) p[k] *= inv;

  float ehv[8];
#pragma unroll
  for (int i = 0; i < 8; i++) ehv[i] = eh[(size_t)m * E_DIM + lane + 64 * i];

  float ka[NTOPK];
#pragma unroll
  for (int k = 0; k < NTOPK; k++) {
    const float* nr = et + (size_t)id[k] * E_DIM;
    float snb = 0.f, sg = 0.f;
    const float aa = 2.f - p[k], bb = p[k];
#pragma unroll
    for (int i = 0; i < 8; i++) {
      const float nv = nr[lane + 64 * i];
      snb += nv;
      sg += tanhf(fmaf(aa, ehv[i], bb * nv));
    }
#pragma unroll
    for (int off = 32; off; off >>= 1) {
      snb += __shfl_xor(snb, off);
      sg += __shfl_xor(sg, off);
    }
    ka[k] = snb * sg;
  }
  float km = ka[0];
#pragma unroll
  for (int k = 1; k < NTOPK; k++) km = fmaxf(km, ka[k]);
  float kp[NTOPK]; float ks = 0.f;
#pragma unroll
  for (int k = 0; k < NTOPK; k++) { kp[k] = expf(ka[k] - km); ks += kp[k]; }
  const float kinv = 1.f / ks;
#pragma unroll
  for (int i = 0; i < 8; i++) {
    float o = 0.f;
#pragma unroll
    for (int k = 0; k < NTOPK; k++)
      o = fmaf(kp[k], et[(size_t)id[k] * E_DIM + lane + 64 * i], o);
    eNh[(size_t)m * E_DIM + lane + 64 * i] = o * kinv;
  }
}

// ---------------------------------------------------------------------------
__global__ __launch_bounds__(256) void gate_g_kernel(
    const float* __restrict__ ahid, const float* __restrict__ a2w,
    const float* __restrict__ a2b, float* __restrict__ g)
{
  const int lane = threadIdx.x & 63;
  const int m = blockIdx.x * 4 + (threadIdx.x >> 6);
  float s = 0.f;
  for (int j = lane; j < 256; j += 64)
    s = fmaf(a2w[j], ahid[(size_t)m * 256 + j], s);
#pragma unroll
  for (int off = 32; off; off >>= 1) s += __shfl_xor(s, off);
  if (lane == 0) g[m] = s + a2b[0];
}

__global__ __launch_bounds__(1024) void softmax_stats_kernel(
    const float* __restrict__ g, float* __restrict__ stats)
{
  __shared__ float red[16];
  __shared__ float red2[16];
  const int t = threadIdx.x;
  float mx = NEG_BIG;
  for (int i = t; i < M_NODES; i += 1024) mx = fmaxf(mx, g[i]);
#pragma unroll
  for (int off = 32; off; off >>= 1) mx = fmaxf(mx, __shfl_xor(mx, off));
  if ((t & 63) == 0) red[t >> 6] = mx;
  __syncthreads();
  float gmx = red[0];
  for (int i = 1; i < 16; i++) gmx = fmaxf(gmx, red[i]);
  float s = 0.f;
  for (int i = t; i < M_NODES; i += 1024) s += expf(g[i] - gmx);
#pragma unroll
  for (int off = 32; off; off >>= 1) s += __shfl_xor(s, off);
  if ((t & 63) == 0) red2[t >> 6] = s;
  __syncthreads();
  if (t == 0) {
    float tot = 0.f;
    for (int i = 0; i < 16; i++) tot += red2[i];
    stats[0] = gmx; stats[1] = tot;
  }
}

__global__ __launch_bounds__(256) void pooled_kernel(
    const float* __restrict__ emb, const float* __restrict__ g,
    const float* __restrict__ stats, float* __restrict__ pooled)
{
  const int t = threadIdx.x;
  const int r0 = blockIdx.x * 128;
  const float mx = stats[0];
  const float inv = 1.f / stats[1];
  float a0 = 0.f, a1 = 0.f;
  for (int r = 0; r < 128; r++) {
    const int m = r0 + r;
    const float wv = expf(g[m] - mx) * inv;
    a0 = fmaf(wv, emb[(size_t)m * E_DIM + t], a0);
    a1 = fmaf(wv, emb[(size_t)m * E_DIM + 256 + t], a1);
  }
  atomicAdd(&pooled[t], a0);
  atomicAdd(&pooled[t + 256], a1);
}

__global__ __launch_bounds__(512) void ln_kernel(
    const float* __restrict__ pooled, const float* __restrict__ lng,
    const float* __restrict__ lnb, float* __restrict__ out)
{
  __shared__ float red[8];
  __shared__ float red2[8];
  const int t = threadIdx.x;
  const float v = pooled[t];
  float s = v;
#pragma unroll
  for (int off = 32; off; off >>= 1) s += __shfl_xor(s, off);
  if ((t & 63) == 0) red[t >> 6] = s;
  __syncthreads();
  float tot = 0.f;
  for (int i = 0; i < 8; i++) tot += red[i];
  const float mu = tot / (float)E_DIM;
  const float d = v - mu;
  float q = d * d;
#pragma unroll
  for (int off = 32; off; off >>= 1) q += __shfl_xor(q, off);
  if ((t & 63) == 0) red2[t >> 6] = q;
  __syncthreads();
  float vt = 0.f;
  for (int i = 0; i < 8; i++) vt += red2[i];
  const float var = vt / (float)E_DIM;
  out[t] = d * rsqrtf(var + 1e-5f) * lng[t] + lnb[t];
}

// ---------------------------------------------------------------------------
extern "C" void kernel_launch(void* const* d_in, const int* in_sizes, int n_in,
                              void* d_out, int out_size, void* d_ws, size_t ws_size,
                              hipStream_t stream)
{
  const float* x     = (const float*)d_in[0];
  const float* fc1_w = (const float*)d_in[1];
  const float* fc1_b = (const float*)d_in[2];
  const float* wh_w  = (const float*)d_in[3];
  const float* wh_b  = (const float*)d_in[4];
  const float* wt_w  = (const float*)d_in[5];
  const float* wt_b  = (const float*)d_in[6];
  const float* l1_w  = (const float*)d_in[7];
  const float* l1_b  = (const float*)d_in[8];
  const float* l2_w  = (const float*)d_in[9];
  const float* l2_b  = (const float*)d_in[10];
  const float* a1_w  = (const float*)d_in[11];
  const float* a1_b  = (const float*)d_in[12];
  const float* a2_w  = (const float*)d_in[13];
  const float* a2_b  = (const float*)d_in[14];
  const float* ln_g  = (const float*)d_in[15];
  const float* ln_b  = (const float*)d_in[16];

  char* ws = (char*)d_ws;
  // Region A [0,16M): h (steps1-3) -> ehT/etT bf16 (cast/attn) -> e_Nh -> ahid
  float* h    = (float*)ws;
  unsigned short* ehT = (unsigned short*)ws;
  unsigned short* etT = (unsigned short*)(ws + (8 << 20));
  float* eNh  = (float*)ws;
  float* ahid = (float*)ws;
  // Region B [16M,32M): e_h fp32 (steps3-6) -> g/stats/pooled (steps8-11)
  float* ehb    = (float*)(ws + (16 << 20));
  float* g      = (float*)(ws + (16 << 20));
  float* stats  = (float*)(ws + (16 << 20) + (64 << 10));
  float* pooled = (float*)(ws + (16 << 20) + (68 << 10));
  // Region C [32M,48M): colsum (step2) -> e_t fp32 (steps3-5) -> emb (steps6-10)
  float* etb    = (float*)(ws + (32 << 20));
  float* colsum = (float*)(ws + (32 << 20));
  float* emb    = etb;
  // Region D [48M, ~49.6M): top-k candidate lists
  float* tkv4 = (float*)(ws + (48 << 20));
  int*   tki4 = (int*)(ws + (48 << 20) + 786432);

  // 1. h = lrelu(x @ fc1_w^T + b)
  gemm_kernel<0, true><<<dim3(E_DIM / 64, M_NODES / 64), 256, 0, stream>>>(
      x, nullptr, fc1_w, nullptr, fc1_b, nullptr, h, nullptr, E_DIM, 384);
  // 2. h = (h + colmean(h)) * 0.5
  hipMemsetAsync(colsum, 0, E_DIM * sizeof(float), stream);
  colsum_kernel<<<M_NODES / 128, 256, 0, stream>>>(h, colsum);
  hupdate_kernel<<<(M_NODES * E_DIM) / (256 * 4), 256, 0, stream>>>(h, colsum);
  // 3. e_h, e_t
  gemm_kernel<1, false><<<dim3(E_DIM / 64, M_NODES / 64), 256, 0, stream>>>(
      h, nullptr, wh_w, wt_w, wh_b, wt_b, ehb, etb, E_DIM, E_DIM);
  // 3b. bf16 frag-tiled casts (eh pre-scaled)
  cast_tiled_kernel<<<dim3((M_NODES * 64) / 256, 2), 256, 0, stream>>>(ehb, etb, ehT, etT);
  // 4. MFMA attn-logit GEMM + streaming top-6 (4 col chunks x 64 row strips)
  attn_mfma_topk<<<dim3(4, 64), 256, 0, stream>>>(ehT, etT, tkv4, tki4);
  // 5. per-row merge + combine -> e_Nh
  combine_kernel<<<M_NODES / 4, 256, 0, stream>>>(ehb, etb, tkv4, tki4, eNh);
  // 6. emb = lrelu((e_h+e_Nh)@l1^T+b1) + lrelu((e_h*e_Nh)@l2^T+b2)
  gemm_kernel<2, true><<<dim3(E_DIM / 64, M_NODES / 64), 256, 0, stream>>>(
      ehb, eNh, l1_w, l2_w, l1_b, l2_b, emb, nullptr, E_DIM, E_DIM);
  // 7. ahid = lrelu(emb @ a1^T + b)  [8192x256]
  gemm_kernel<0, true><<<dim3(256 / 64, M_NODES / 64), 256, 0, stream>>>(
      emb, nullptr, a1_w, nullptr, a1_b, nullptr, ahid, nullptr, 256, E_DIM);
  hipMemsetAsync(pooled, 0, E_DIM * sizeof(float), stream);
  // 8. g[m] = a2 . ahid[m] + a2_b
  gate_g_kernel<<<M_NODES / 4, 256, 0, stream>>>(ahid, a2_w, a2_b, g);
  // 9. softmax stats over M
  softmax_stats_kernel<<<1, 1024, 0, stream>>>(g, stats);
  // 10. pooled = sum_m att[m] * emb[m]
  pooled_kernel<<<M_NODES / 128, 256, 0, stream>>>(emb, g, stats, pooled);
  // 11. layernorm -> out
  ln_kernel<<<1, 512, 0, stream>>>(pooled, ln_g, ln_b, (float*)d_out);
}

// Round 3
// 660.932 us; speedup vs baseline: 6.5160x; 1.4784x over previous
//
#include <hip/hip_runtime.h>
#include <math.h>
#include <stdint.h>

#define M_NODES 8192
#define E_DIM   512
#define NTOPK   6
#define ATTN_SCALE 0.04419417382415922f  // 512^-0.5
#define NEG_BIG (-1e38f)

typedef __attribute__((ext_vector_type(8))) short short8;
typedef __attribute__((ext_vector_type(4))) float f32x4;

__device__ __forceinline__ float lrelu(float v) { return v > 0.f ? v : 0.01f * v; }

__device__ __forceinline__ unsigned short f2bf(float f) {
  uint32_t u = __float_as_uint(f);
  uint32_t r = (u + 0x7FFFu + ((u >> 16) & 1u)) >> 16;
  return (unsigned short)r;
}
__device__ __forceinline__ float bf2f(unsigned short s) {
  return __uint_as_float(((uint32_t)s) << 16);
}

// async 16B/lane global->LDS (wave-uniform LDS base, lane i lands at base+16i)
__device__ __forceinline__ void async_cp16(const void* gptr, void* lds) {
  auto g1 = reinterpret_cast<const __attribute__((address_space(1))) unsigned int*>(
      reinterpret_cast<uintptr_t>(gptr));
  auto l3 = reinterpret_cast<__attribute__((address_space(3))) unsigned int*>(
      reinterpret_cast<uintptr_t>(lds));
  __builtin_amdgcn_global_load_lds(g1, l3, 16, 0, 0);
}

// tiled bf16 layout: value (m,k), Ktiles=K/32:
//   idx = ((m>>4)*Ktiles + (k>>5))*512 + ((m&15) + 16*((k>>3)&3))*8 + (k&7)

// ---------------------------------------------------------------------------
// Cast fp32 x + 6 weight matrices into bf16 frag-tiled layout. One granule
// (8 k-values of one row) per thread; if-chain over concatenated ranges.
// ---------------------------------------------------------------------------
__global__ __launch_bounds__(256) void wcast_kernel(
    const float* __restrict__ x, const float* __restrict__ fc1w,
    const float* __restrict__ whw, const float* __restrict__ wtw,
    const float* __restrict__ l1w, const float* __restrict__ l2w,
    const float* __restrict__ a1w,
    unsigned short* __restrict__ xT, unsigned short* __restrict__ fc1T,
    unsigned short* __restrict__ whT, unsigned short* __restrict__ wtT,
    unsigned short* __restrict__ l1T, unsigned short* __restrict__ l2T,
    unsigned short* __restrict__ a1T)
{
  const int gid = blockIdx.x * 256 + threadIdx.x;  // 0 .. 565247
  const float* src; unsigned short* dst; int K8, local;
  if (gid < 417792) {
    K8 = 48;
    if (gid < 393216) { src = x; dst = xT; local = gid; }
    else { src = fc1w; dst = fc1T; local = gid - 393216; }
  } else {
    K8 = 64;
    if (gid < 450560)      { src = whw; dst = whT; local = gid - 417792; }
    else if (gid < 483328) { src = wtw; dst = wtT; local = gid - 450560; }
    else if (gid < 516096) { src = l1w; dst = l1T; local = gid - 483328; }
    else if (gid < 548864) { src = l2w; dst = l2T; local = gid - 516096; }
    else                   { src = a1w; dst = a1T; local = gid - 548864; }
  }
  const int m = local / K8;
  const int k8 = local - m * K8;
  const float* p = src + (size_t)m * (K8 * 8) + k8 * 8;
  float4 v0 = ((const float4*)p)[0];
  float4 v1 = ((const float4*)p)[1];
  const int Kt = K8 >> 2;
  const size_t ti = ((size_t)(m >> 4) * Kt + (k8 >> 2)) * 512 + ((m & 15) + 16 * (k8 & 3)) * 8;
  uint4 pk;
  pk.x = (uint32_t)f2bf(v0.x) | ((uint32_t)f2bf(v0.y) << 16);
  pk.y = (uint32_t)f2bf(v0.z) | ((uint32_t)f2bf(v0.w) << 16);
  pk.z = (uint32_t)f2bf(v1.x) | ((uint32_t)f2bf(v1.y) << 16);
  pk.w = (uint32_t)f2bf(v1.z) | ((uint32_t)f2bf(v1.w) << 16);
  *(uint4*)(dst + ti) = pk;
}

// ---------------------------------------------------------------------------
// MFMA GEMM, tile 128(M) x 64(N), 4 waves each 32x64, K-step 32.
// MODE 0: Cf = lrelu(A@W1^T + b1)
// MODE 1: Cf = A@W1^T+b1 ; T1 = bf16(Cf*scaleT) tiled ; T2 = bf16(A@W2^T+b2) tiled
// MODE 2: Cf = lrelu(A1@W1^T+b1)+lrelu(A2@W2^T+b2) ; T1 = bf16(Cf) tiled
// ---------------------------------------------------------------------------
template <int MODE>
__global__ __launch_bounds__(256) void mfma_gemm(
    const unsigned short* __restrict__ At1, const unsigned short* __restrict__ At2,
    const unsigned short* __restrict__ Wt1, const unsigned short* __restrict__ Wt2,
    const float* __restrict__ b1, const float* __restrict__ b2,
    float* __restrict__ Cf, unsigned short* __restrict__ T1,
    unsigned short* __restrict__ T2, float scaleT, int N, int K)
{
  __shared__ unsigned short As[2][8 * 512];
  __shared__ unsigned short Bs[2][4 * 512];
  const int Kt = K >> 5;
  const int tid = threadIdx.x, lane = tid & 63, w = tid >> 6;
  const int m0 = blockIdx.y * 128, n0 = blockIdx.x * 64;

  f32x4 acc0[2][4], acc1[2][4];
#pragma unroll
  for (int p = 0; p < 2; p++)
#pragma unroll
    for (int j = 0; j < 4; j++) {
      acc0[p][j] = (f32x4){0.f, 0.f, 0.f, 0.f};
      acc1[p][j] = (f32x4){0.f, 0.f, 0.f, 0.f};
    }

  for (int kt = 0; kt < Kt; kt++) {
    const unsigned short* a1p = At1 + ((size_t)((m0 >> 4) + 2 * w) * Kt + kt) * 512 + lane * 8;
    async_cp16(a1p, &As[0][(2 * w) * 512]);
    async_cp16(a1p + (size_t)Kt * 512, &As[0][(2 * w + 1) * 512]);
    if (MODE == 2) {
      const unsigned short* a2p = At2 + ((size_t)((m0 >> 4) + 2 * w) * Kt + kt) * 512 + lane * 8;
      async_cp16(a2p, &As[1][(2 * w) * 512]);
      async_cp16(a2p + (size_t)Kt * 512, &As[1][(2 * w + 1) * 512]);
    }
    const unsigned short* bp1 = Wt1 + ((size_t)((n0 >> 4) + w) * Kt + kt) * 512 + lane * 8;
    async_cp16(bp1, &Bs[0][w * 512]);
    if (MODE >= 1) {
      const unsigned short* bp2 = Wt2 + ((size_t)((n0 >> 4) + w) * Kt + kt) * 512 + lane * 8;
      async_cp16(bp2, &Bs[1][w * 512]);
    }
    __syncthreads();
    short8 a[2], a2[2], bb[4], bb2[4];
#pragma unroll
    for (int p = 0; p < 2; p++) a[p] = *(const short8*)&As[0][(2 * w + p) * 512 + lane * 8];
    if (MODE == 2) {
#pragma unroll
      for (int p = 0; p < 2; p++) a2[p] = *(const short8*)&As[1][(2 * w + p) * 512 + lane * 8];
    }
#pragma unroll
    for (int j = 0; j < 4; j++) bb[j] = *(const short8*)&Bs[0][j * 512 + lane * 8];
    if (MODE >= 1) {
#pragma unroll
      for (int j = 0; j < 4; j++) bb2[j] = *(const short8*)&Bs[1][j * 512 + lane * 8];
    }
#pragma unroll
    for (int p = 0; p < 2; p++)
#pragma unroll
      for (int j = 0; j < 4; j++) {
        acc0[p][j] = __builtin_amdgcn_mfma_f32_16x16x32_bf16(a[p], bb[j], acc0[p][j], 0, 0, 0);
        if (MODE == 1)
          acc1[p][j] = __builtin_amdgcn_mfma_f32_16x16x32_bf16(a[p], bb2[j], acc1[p][j], 0, 0, 0);
        if (MODE == 2)
          acc1[p][j] = __builtin_amdgcn_mfma_f32_16x16x32_bf16(a2[p], bb2[j], acc1[p][j], 0, 0, 0);
      }
    __syncthreads();
  }

  const int lrow = (lane >> 4) * 4, lcol = lane & 15;
  const int NT = N >> 5;  // Ktiles of the next layer's tiled tensors
#pragma unroll
  for (int p = 0; p < 2; p++)
#pragma unroll
    for (int j = 0; j < 4; j++) {
      const int c = n0 + j * 16 + lcol;
      const float bias1 = b1[c];
      const float bias2 = (MODE >= 1) ? b2[c] : 0.f;
#pragma unroll
      for (int d = 0; d < 4; d++) {
        const int r = m0 + w * 32 + p * 16 + lrow + d;
        const float v0 = acc0[p][j][d] + bias1;
        if (MODE == 0) {
          Cf[(size_t)r * N + c] = lrelu(v0);
        } else {
          const size_t ti = ((size_t)(r >> 4) * NT + (c >> 5)) * 512 +
                            ((r & 15) + 16 * ((c >> 3) & 3)) * 8 + (c & 7);
          if (MODE == 1) {
            Cf[(size_t)r * N + c] = v0;
            T1[ti] = f2bf(v0 * scaleT);
            T2[ti] = f2bf(acc1[p][j][d] + bias2);
          } else {
            const float e = lrelu(v0) + lrelu(acc1[p][j][d] + bias2);
            Cf[(size_t)r * N + c] = e;
            T1[ti] = f2bf(e);
          }
        }
      }
    }
}

// ---------------------------------------------------------------------------
// Column sum of h over M
// ---------------------------------------------------------------------------
__global__ __launch_bounds__(256) void colsum_kernel(const float* __restrict__ h,
                                                     float* __restrict__ colsum)
{
  const int t = threadIdx.x;
  const int r0 = blockIdx.x * 128;
  float s0 = 0.f, s1 = 0.f;
  for (int r = 0; r < 128; r++) {
    s0 += h[(size_t)(r0 + r) * E_DIM + t];
    s1 += h[(size_t)(r0 + r) * E_DIM + 256 + t];
  }
  atomicAdd(&colsum[t], s0);
  atomicAdd(&colsum[t + 256], s1);
}

// h' = (h + colmean)*0.5 fused with bf16 tiled cast (Ktiles=16)
__global__ __launch_bounds__(256) void hupd_cast_kernel(
    const float* __restrict__ h, const float* __restrict__ colsum,
    unsigned short* __restrict__ hT)
{
  const int gid = blockIdx.x * 256 + threadIdx.x;  // 8192*64
  const int m = gid >> 6, k8 = gid & 63;
  const float* p = h + (size_t)m * E_DIM + k8 * 8;
  float4 v0 = ((const float4*)p)[0];
  float4 v1 = ((const float4*)p)[1];
  float4 c0 = *(const float4*)(colsum + k8 * 8);
  float4 c1 = *(const float4*)(colsum + k8 * 8 + 4);
  const float im = 1.f / (float)M_NODES;
  v0.x = (v0.x + c0.x * im) * 0.5f; v0.y = (v0.y + c0.y * im) * 0.5f;
  v0.z = (v0.z + c0.z * im) * 0.5f; v0.w = (v0.w + c0.w * im) * 0.5f;
  v1.x = (v1.x + c1.x * im) * 0.5f; v1.y = (v1.y + c1.y * im) * 0.5f;
  v1.z = (v1.z + c1.z * im) * 0.5f; v1.w = (v1.w + c1.w * im) * 0.5f;
  const size_t ti = ((size_t)(m >> 4) * 16 + (k8 >> 2)) * 512 + ((m & 15) + 16 * (k8 & 3)) * 8;
  uint4 pk;
  pk.x = (uint32_t)f2bf(v0.x) | ((uint32_t)f2bf(v0.y) << 16);
  pk.y = (uint32_t)f2bf(v0.z) | ((uint32_t)f2bf(v0.w) << 16);
  pk.z = (uint32_t)f2bf(v1.x) | ((uint32_t)f2bf(v1.y) << 16);
  pk.w = (uint32_t)f2bf(v1.z) | ((uint32_t)f2bf(v1.w) << 16);
  *(uint4*)(hT + ti) = pk;
}

// ---------------------------------------------------------------------------
// Streaming top-6 state
// ---------------------------------------------------------------------------
struct Top6 { float v[NTOPK]; int id[NTOPK]; float cmin; int cslot; };
__device__ __forceinline__ void t6_init(Top6& t) {
#pragma unroll
  for (int k = 0; k < NTOPK; k++) { t.v[k] = NEG_BIG; t.id[k] = 0; }
  t.cmin = NEG_BIG; t.cslot = 0;
}
__device__ __forceinline__ void t6_ins(Top6& t, float vv, int ii) {
  if (vv > t.cmin) {
    t.v[t.cslot] = vv; t.id[t.cslot] = ii;
    t.cmin = t.v[0]; t.cslot = 0;
#pragma unroll
    for (int k = 1; k < NTOPK; k++)
      if (t.v[k] < t.cmin) { t.cmin = t.v[k]; t.cslot = k; }
  }
}

// ---------------------------------------------------------------------------
// bf16 MFMA attn-logit GEMM + streaming top-6. grid (16 chunks, 64 strips).
// Per block: 128 rows x 512 cols (4 col-tiles of 128). Sc stored bf16 ->
// 51.5KB LDS -> 3 blocks/CU. Output: packed (bf16<<16|idx) per-chunk top-6.
// ---------------------------------------------------------------------------
__global__ __launch_bounds__(256) void attn_mfma_topk(
    const unsigned short* __restrict__ ehT, const unsigned short* __restrict__ etT,
    unsigned int* __restrict__ tkp)
{
  __shared__ unsigned short As[8 * 512];
  __shared__ unsigned short Bs[8 * 512];
  __shared__ unsigned short Sc[128 * 136];
  const int tid = threadIdx.x;
  const int lane = tid & 63;
  const int w = tid >> 6;
  const int wr = w >> 1, wc = w & 1;
  const int m0 = blockIdx.y * 128;
  const int cbase = blockIdx.x * 512;

  const int r = tid & 127;
  const int hc = tid >> 7;

  Top6 t; t6_init(t);

  const int lrow = (lane >> 4) * 4;
  const int lcol = lane & 15;

  for (int ct = 0; ct < 4; ct++) {
    const int n0 = cbase + ct * 128;
    f32x4 acc[4][4];
#pragma unroll
    for (int i = 0; i < 4; i++)
#pragma unroll
      for (int j = 0; j < 4; j++) acc[i][j] = (f32x4){0.f, 0.f, 0.f, 0.f};

    for (int kt = 0; kt < 16; kt++) {
      const int s0 = w, s1 = w + 4;
      async_cp16(ehT + ((size_t)((m0 >> 4) + s0) * 16 + kt) * 512 + lane * 8, &As[s0 * 512]);
      async_cp16(ehT + ((size_t)((m0 >> 4) + s1) * 16 + kt) * 512 + lane * 8, &As[s1 * 512]);
      async_cp16(etT + ((size_t)((n0 >> 4) + s0) * 16 + kt) * 512 + lane * 8, &Bs[s0 * 512]);
      async_cp16(etT + ((size_t)((n0 >> 4) + s1) * 16 + kt) * 512 + lane * 8, &Bs[s1 * 512]);
      __syncthreads();
      short8 a[4], b[4];
#pragma unroll
      for (int i = 0; i < 4; i++) a[i] = *(const short8*)&As[(wr * 4 + i) * 512 + lane * 8];
#pragma unroll
      for (int j = 0; j < 4; j++) b[j] = *(const short8*)&Bs[(wc * 4 + j) * 512 + lane * 8];
#pragma unroll
      for (int i = 0; i < 4; i++)
#pragma unroll
        for (int j = 0; j < 4; j++)
          acc[i][j] = __builtin_amdgcn_mfma_f32_16x16x32_bf16(a[i], b[j], acc[i][j], 0, 0, 0);
      __syncthreads();
    }

    // scores -> LDS as bf16 (C layout: col=lane&15, row=quad*4+reg)
#pragma unroll
    for (int i = 0; i < 4; i++) {
      const int row = wr * 64 + i * 16 + lrow;
#pragma unroll
      for (int j = 0; j < 4; j++) {
        const int col = wc * 64 + j * 16 + lcol;
        Sc[(row + 0) * 136 + col] = f2bf(acc[i][j][0]);
        Sc[(row + 1) * 136 + col] = f2bf(acc[i][j][1]);
        Sc[(row + 2) * 136 + col] = f2bf(acc[i][j][2]);
        Sc[(row + 3) * 136 + col] = f2bf(acc[i][j][3]);
      }
    }
    __syncthreads();

    // per-row scan of 64 cols
    const unsigned short* srow = &Sc[r * 136 + hc * 64];
    const int cg0 = n0 + hc * 64;
#pragma unroll
    for (int g = 0; g < 8; g++) {
      short8 u = *(const short8*)(srow + g * 8);
      const int cg = cg0 + g * 8;
#pragma unroll
      for (int e = 0; e < 8; e++)
        t6_ins(t, bf2f((unsigned short)u[e]), cg + e);
    }
    // Sc reuse ordered by next ct's K-loop barriers
  }

  // merge the two col-half lists per row through LDS (float scratch over Sc)
  __syncthreads();
  float* scf = (float*)Sc;
  if (hc == 1) {
#pragma unroll
    for (int k = 0; k < NTOPK; k++) {
      scf[r * 16 + k] = t.v[k];
      scf[r * 16 + 8 + k] = __int_as_float(t.id[k]);
    }
  }
  __syncthreads();
  if (hc == 0) {
#pragma unroll
    for (int k = 0; k < NTOPK; k++)
      t6_ins(t, scf[r * 16 + k], __float_as_int(scf[r * 16 + 8 + k]));
    const size_t base = ((size_t)(m0 + r) * 16 + blockIdx.x) * NTOPK;
#pragma unroll
    for (int k = 0; k < NTOPK; k++)
      tkp[base + k] = ((uint32_t)f2bf(t.v[k]) << 16) | (uint32_t)t.id[k];
  }
}

// ---------------------------------------------------------------------------
// Per-row: merge 16 chunk lists -> top-6, softmax, gather Nb from etT (bf16
// tiled), gate tanh, ka softmax, e_Nh; write s1=eh+eNh, s2=eh*eNh bf16 tiled.
// One wave per row.
// ---------------------------------------------------------------------------
__global__ __launch_bounds__(256) void combine_kernel(
    const float* __restrict__ ehb, const unsigned short* __restrict__ etT,
    const unsigned int* __restrict__ tkp,
    unsigned short* __restrict__ s1T, unsigned short* __restrict__ s2T)
{
  const int lane = threadIdx.x & 63;
  const int m = blockIdx.x * 4 + (threadIdx.x >> 6);

  Top6 t; t6_init(t);
  const unsigned int* lst = tkp + (size_t)m * 96;
  for (int l = 0; l < 96; l++) {
    const unsigned int u = lst[l];
    t6_ins(t, __uint_as_float(u & 0xFFFF0000u), (int)(u & 0xFFFFu));
  }

  float wv[NTOPK]; int id[NTOPK];
#pragma unroll
  for (int k = 0; k < NTOPK; k++) { wv[k] = t.v[k]; id[k] = t.id[k]; }

  float mx = wv[0];
#pragma unroll
  for (int k = 1; k < NTOPK; k++) mx = fmaxf(mx, wv[k]);
  float p[NTOPK]; float s = 0.f;
#pragma unroll
  for (int k = 0; k < NTOPK; k++) { p[k] = expf(wv[k] - mx); s += p[k]; }
  const float inv = 1.f / s;
#pragma unroll
  for (int k = 0; k < NTOPK; k++) p[k] *= inv;

  float ehv[8];
#pragma unroll
  for (int i = 0; i < 8; i++) ehv[i] = ehb[(size_t)m * E_DIM + lane + 64 * i];

  // gather neighbors from etT (bf16 tiled); within-granule offset constant in i
  const int wconst_base = 16 * ((lane >> 3) & 3) * 8 + (lane & 7);
  float nv[NTOPK][8];
#pragma unroll
  for (int k = 0; k < NTOPK; k++) {
    const int n = id[k];
    const unsigned short* bp = etT + ((size_t)(n >> 4) * 16 + (lane >> 5)) * 512 +
                               (n & 15) * 8 + wconst_base;
#pragma unroll
    for (int i = 0; i < 8; i++) nv[k][i] = bf2f(bp[i * 1024]);
  }

  float ka[NTOPK];
#pragma unroll
  for (int k = 0; k < NTOPK; k++) {
    float snb = 0.f, sg = 0.f;
    const float aa = 2.f - p[k], bb = p[k];
#pragma unroll
    for (int i = 0; i < 8; i++) {
      snb += nv[k][i];
      sg += tanhf(fmaf(aa, ehv[i], bb * nv[k][i]));
    }
#pragma unroll
    for (int off = 32; off; off >>= 1) {
      snb += __shfl_xor(snb, off);
      sg += __shfl_xor(sg, off);
    }
    ka[k] = snb * sg;
  }
  float km = ka[0];
#pragma unroll
  for (int k = 1; k < NTOPK; k++) km = fmaxf(km, ka[k]);
  float kp[NTOPK]; float ks = 0.f;
#pragma unroll
  for (int k = 0; k < NTOPK; k++) { kp[k] = expf(ka[k] - km); ks += kp[k]; }
  const float kinv = 1.f / ks;

  unsigned short* o1 = s1T + ((size_t)(m >> 4) * 16 + (lane >> 5)) * 512 +
                       (m & 15) * 8 + wconst_base;
  unsigned short* o2 = s2T + ((size_t)(m >> 4) * 16 + (lane >> 5)) * 512 +
                       (m & 15) * 8 + wconst_base;
#pragma unroll
  for (int i = 0; i < 8; i++) {
    float o = 0.f;
#pragma unroll
    for (int k = 0; k < NTOPK; k++) o = fmaf(kp[k], nv[k][i], o);
    o *= kinv;
    o1[i * 1024] = f2bf(ehv[i] + o);
    o2[i * 1024] = f2bf(ehv[i] * o);
  }
}

// ---------------------------------------------------------------------------
__global__ __launch_bounds__(256) void gate_g_kernel(
    const float* __restrict__ ahid, const float* __restrict__ a2w,
    const float* __restrict__ a2b, float* __restrict__ g)
{
  const int lane = threadIdx.x & 63;
  const int m = blockIdx.x * 4 + (threadIdx.x >> 6);
  float s = 0.f;
  for (int j = lane; j < 256; j += 64)
    s = fmaf(a2w[j], ahid[(size_t)m * 256 + j], s);
#pragma unroll
  for (int off = 32; off; off >>= 1) s += __shfl_xor(s, off);
  if (lane == 0) g[m] = s + a2b[0];
}

__global__ __launch_bounds__(1024) void softmax_stats_kernel(
    const float* __restrict__ g, float* __restrict__ stats)
{
  __shared__ float red[16];
  __shared__ float red2[16];
  const int t = threadIdx.x;
  float mx = NEG_BIG;
  for (int i = t; i < M_NODES; i += 1024) mx = fmaxf(mx, g[i]);
#pragma unroll
  for (int off = 32; off; off >>= 1) mx = fmaxf(mx, __shfl_xor(mx, off));
  if ((t & 63) == 0) red[t >> 6] = mx;
  __syncthreads();
  float gmx = red[0];
  for (int i = 1; i < 16; i++) gmx = fmaxf(gmx, red[i]);
  float s = 0.f;
  for (int i = t; i < M_NODES; i += 1024) s += expf(g[i] - gmx);
#pragma unroll
  for (int off = 32; off; off >>= 1) s += __shfl_xor(s, off);
  if ((t & 63) == 0) red2[t >> 6] = s;
  __syncthreads();
  if (t == 0) {
    float tot = 0.f;
    for (int i = 0; i < 16; i++) tot += red2[i];
    stats[0] = gmx; stats[1] = tot;
  }
}

__global__ __launch_bounds__(256) void pooled_kernel(
    const float* __restrict__ emb, const float* __restrict__ g,
    const float* __restrict__ stats, float* __restrict__ pooled)
{
  const int t = threadIdx.x;
  const int r0 = blockIdx.x * 128;
  const float mx = stats[0];
  const float inv = 1.f / stats[1];
  float a0 = 0.f, a1 = 0.f;
  for (int r = 0; r < 128; r++) {
    const int m = r0 + r;
    const float wv = expf(g[m] - mx) * inv;
    a0 = fmaf(wv, emb[(size_t)m * E_DIM + t], a0);
    a1 = fmaf(wv, emb[(size_t)m * E_DIM + 256 + t], a1);
  }
  atomicAdd(&pooled[t], a0);
  atomicAdd(&pooled[t + 256], a1);
}

__global__ __launch_bounds__(512) void ln_kernel(
    const float* __restrict__ pooled, const float* __restrict__ lng,
    const float* __restrict__ lnb, float* __restrict__ out)
{
  __shared__ float red[8];
  __shared__ float red2[8];
  const int t = threadIdx.x;
  const float v = pooled[t];
  float s = v;
#pragma unroll
  for (int off = 32; off; off >>= 1) s += __shfl_xor(s, off);
  if ((t & 63) == 0) red[t >> 6] = s;
  __syncthreads();
  float tot = 0.f;
  for (int i = 0; i < 8; i++) tot += red[i];
  const float mu = tot / (float)E_DIM;
  const float d = v - mu;
  float q = d * d;
#pragma unroll
  for (int off = 32; off; off >>= 1) q += __shfl_xor(q, off);
  if ((t & 63) == 0) red2[t >> 6] = q;
  __syncthreads();
  float vt = 0.f;
  for (int i = 0; i < 8; i++) vt += red2[i];
  const float var = vt / (float)E_DIM;
  out[t] = d * rsqrtf(var + 1e-5f) * lng[t] + lnb[t];
}

// ---------------------------------------------------------------------------
extern "C" void kernel_launch(void* const* d_in, const int* in_sizes, int n_in,
                              void* d_out, int out_size, void* d_ws, size_t ws_size,
                              hipStream_t stream)
{
  const float* x     = (const float*)d_in[0];
  const float* fc1_w = (const float*)d_in[1];
  const float* fc1_b = (const float*)d_in[2];
  const float* wh_w  = (const float*)d_in[3];
  const float* wh_b  = (const float*)d_in[4];
  const float* wt_w  = (const float*)d_in[5];
  const float* wt_b  = (const float*)d_in[6];
  const float* l1_w  = (const float*)d_in[7];
  const float* l1_b  = (const float*)d_in[8];
  const float* l2_w  = (const float*)d_in[9];
  const float* l2_b  = (const float*)d_in[10];
  const float* a1_w  = (const float*)d_in[11];
  const float* a1_b  = (const float*)d_in[12];
  const float* a2_w  = (const float*)d_in[13];
  const float* a2_b  = (const float*)d_in[14];
  const float* ln_g  = (const float*)d_in[15];
  const float* ln_b  = (const float*)d_in[16];

  char* ws = (char*)d_ws;
  // weight tiles [0, 2.75M)
  unsigned short* fc1T = (unsigned short*)(ws + 0);
  unsigned short* whT  = (unsigned short*)(ws + 393216);
  unsigned short* wtT  = (unsigned short*)(ws + 917504);
  unsigned short* l1T  = (unsigned short*)(ws + 1441792);
  unsigned short* l2T  = (unsigned short*)(ws + 1966080);
  unsigned short* a1T  = (unsigned short*)(ws + 2490368);
  // overlaid activation regions (liveness-checked):
  unsigned short* xT   = (unsigned short*)(ws + 3145728);   // [3M,9M) wcast->gemm1
  unsigned short* ehT  = (unsigned short*)(ws + 3145728);   // [3M,11M) gemm2->attn
  unsigned short* s2T  = (unsigned short*)(ws + 3145728);   // [3M,11M) combine->gemm3
  float*          h    = (float*)(ws + 9437184);            // [9M,25M) gemm1->hupd
  unsigned short* etT  = (unsigned short*)(ws + 11534336);  // [11M,19M) gemm2->combine
  unsigned short* embT = (unsigned short*)(ws + 11534336);  // [11M,19M) gemm3->gemm4
  unsigned int*   tkp  = (unsigned int*)(ws + 19922944);    // [19M,22M) attn->combine
  unsigned short* hT   = (unsigned short*)(ws + 26214400);  // [25M,33M) hupd->gemm2
  unsigned short* s1T  = (unsigned short*)(ws + 26214400);  // [25M,33M) combine->gemm3
  float*          ahid = (float*)(ws + 26214400);           // [25M,33M) gemm4->gate
  float*          ehb  = (float*)(ws + 34603008);           // [33M,49M) gemm2->combine
  float*          embf = (float*)(ws + 34603008);           // [33M,49M) gemm3->pooled
  char*           smal = ws + 51380224;
  float* colsum = (float*)smal;
  float* g      = (float*)(smal + 4096);
  float* stats  = (float*)(smal + 36864);
  float* pooled = (float*)(smal + 40960);

  hipMemsetAsync(smal, 0, 43008, stream);

  // 0. cast x + all weights to bf16 tiled
  wcast_kernel<<<2208, 256, 0, stream>>>(x, fc1_w, wh_w, wt_w, l1_w, l2_w, a1_w,
                                         xT, fc1T, whT, wtT, l1T, l2T, a1T);
  // 1. h = lrelu(x @ fc1^T + b)
  mfma_gemm<0><<<dim3(8, 64), 256, 0, stream>>>(
      xT, nullptr, fc1T, nullptr, fc1_b, nullptr, h, nullptr, nullptr, 1.f, 512, 384);
  // 2. colmean + mix + bf16 tiled cast
  colsum_kernel<<<64, 256, 0, stream>>>(h, colsum);
  hupd_cast_kernel<<<2048, 256, 0, stream>>>(h, colsum, hT);
  // 3. e_h (fp32 + scaled bf16 tiled) and e_t (bf16 tiled)
  mfma_gemm<1><<<dim3(8, 64), 256, 0, stream>>>(
      hT, nullptr, whT, wtT, wh_b, wt_b, ehb, ehT, etT, ATTN_SCALE, 512, 512);
  // 4. MFMA attn-logit GEMM + per-chunk top-6 (16 chunks x 64 strips)
  attn_mfma_topk<<<dim3(16, 64), 256, 0, stream>>>(ehT, etT, tkp);
  // 5. merge + combine -> s1T, s2T (bf16 tiled)
  combine_kernel<<<M_NODES / 4, 256, 0, stream>>>(ehb, etT, tkp, s1T, s2T);
  // 6. emb = lrelu(s1@l1^T+b1)+lrelu(s2@l2^T+b2) -> fp32 + bf16 tiled
  mfma_gemm<2><<<dim3(8, 64), 256, 0, stream>>>(
      s1T, s2T, l1T, l2T, l1_b, l2_b, embf, embT, nullptr, 1.f, 512, 512);
  // 7. ahid = lrelu(emb @ a1^T + b)  [8192x256]
  mfma_gemm<0><<<dim3(4, 64), 256, 0, stream>>>(
      embT, nullptr, a1T, nullptr, a1_b, nullptr, ahid, nullptr, nullptr, 1.f, 256, 512);
  // 8-11. readout
  gate_g_kernel<<<M_NODES / 4, 256, 0, stream>>>(ahid, a2_w, a2_b, g);
  softmax_stats_kernel<<<1, 1024, 0, stream>>>(g, stats);
  pooled_kernel<<<64, 256, 0, stream>>>(embf, g, stats, pooled);
  ln_kernel<<<1, 512, 0, stream>>>(pooled, ln_g, ln_b, (float*)d_out);
}